// Round 6
// baseline (92.003 us; speedup 1.0000x reference)
//
#include <hip/hip_runtime.h>
#include <stdint.h>

constexpr int L_LEVELS = 16;
constexpr int T_SIZE   = 16384;
constexpr int N_PTS    = 262144;

typedef _Float16 h2 __attribute__((ext_vector_type(2)));
typedef _Float16 h8 __attribute__((ext_vector_type(8)));

// Byte-offset-scaled hash constants: prime*4 mod 2^32, mask (T-1)*4.
constexpr uint32_t P1_4 = 2654435761u * 4u;
constexpr uint32_t P2_4 = 805459861u * 4u;
constexpr uint32_t M4   = (T_SIZE - 1) * 4u;   // 65532

__device__ __forceinline__ h2 lerp2(h2 a, h2 b, h2 t) {
    return a + t * (b - a);                     // v_pk_sub + v_pk_fma
}

// ---------------------------------------------------------------------------
// Session ledger driving this round:
//  * 256 MiB poison fill (~45 us) is UNCONDITIONAL -> fixed floor; ws unused.
//  * A ~= 30 us across R0/R4/R5 regardless of staging format (f32 vs fp16)
//    and occupancy (8 vs 16 waves): staging is off the critical path; A is
//    DS-LATENCY-bound (8 outstanding ds_reads/wave, then waitcnt+lerp).
//    DS throughput floor is ~10-13 us -> hide latency with more ILP.
//  * B + cvt ~= 11 us exist only to fix the (n,l) layout.
// This round: ONE kernel.
//  (1) Point-PAIR gather batching: 16 ds_read_b32 in flight per wave
//      (2x ILP), then two lerp trees. VGPR ~115 < 128 cap at (512,4).
//  (2) Direct f32 (n,l) stores. Scattered 8B@128B-stride is clean IF all
//      16 levels of a chunk accumulate in one L2 before eviction: grid
//      swizzle chunk=(bid&7)+(bid>>7)*8, l=(bid>>3)&15 puts all 16
//      level-blocks of a chunk on ONE XCD (bid%8 invariant), dispatch-
//      adjacent; per-XCD write footprint 4 chunks x 512KB = 2MB < 4MB L2
//      -> lines fully written -> no partial-line amplification.
// ---------------------------------------------------------------------------
__global__ __launch_bounds__(512, 4) void hash_encode_direct(
    const float* __restrict__ x,
    const float* __restrict__ emb,    // (L, T, 2) f32
    float2*      __restrict__ out)    // (N, L) float2
{
    __shared__ h2 tab[T_SIZE];        // 64 KB -> 2 blocks/CU, 16 waves/CU

    const int bid   = blockIdx.x;
    const int l     = (bid >> 3) & 15;               // level
    const int chunk = (bid & 7) + ((bid >> 7) << 3); // 0..63, XCD-grouped
    const int t     = threadIdx.x;                   // 0..511
    const int n0    = chunk * 4096 + t * 8;          // 8 consecutive points

    // Stage table l: f32 -> fp16, 4096 h8 groups, 8 per thread (R0-proven).
    {
        const float4* __restrict__ src =
            reinterpret_cast<const float4*>(emb + (size_t)l * T_SIZE * 2);
        h8* __restrict__ d8 = reinterpret_cast<h8*>(tab);
#pragma unroll
        for (int it = 0; it < 8; ++it) {
            const int i = it * 512 + t;              // < 4096
            float4 a = src[2 * i];
            float4 b = src[2 * i + 1];
            h8 w = { (_Float16)a.x, (_Float16)a.y, (_Float16)a.z, (_Float16)a.w,
                     (_Float16)b.x, (_Float16)b.y, (_Float16)b.z, (_Float16)b.w };
            d8[i] = w;                               // ds_write_b128
        }
    }

    // This thread's 8 points: 96 B contiguous = 6 float4, kept in VGPRs.
    union { float4 q[6]; float f[24]; } xs;
    {
        const float4* __restrict__ xv =
            reinterpret_cast<const float4*>(x + (size_t)n0 * 3);
#pragma unroll
        for (int i = 0; i < 6; ++i) xs.q[i] = xv[i];
    }
    __syncthreads();

    // N_l = 16 * 2^(5l/16).
    const float Nl = 16.0f * exp2f((float)l * 0.3125f);
    const char* __restrict__ tb = reinterpret_cast<const char*>(tab);

#pragma unroll
    for (int pp = 0; pp < 8; pp += 2) {
        // ---- phase 1: both points' addresses + weights (pure VALU) ----
        uint32_t off[2], dd0[2], dd1[2], dd2[2];
        h2 tt0[2], tt1[2], tt2[2];
#pragma unroll
        for (int k = 0; k < 2; ++k) {
            const int p = pp + k;
            const float u0 = xs.f[3 * p + 0] * Nl;
            const float u1 = xs.f[3 * p + 1] * Nl;
            const float u2 = xs.f[3 * p + 2] * Nl;

            // u >= 0: df = u - floor(u); exact-integer case gives df=0
            // which zeroes the wrong-slot hi-corner lerp term -> correct.
            const float fl0 = floorf(u0), fl1 = floorf(u1), fl2 = floorf(u2);
            const float df0 = u0 - fl0, df1 = u1 - fl1, df2 = u2 - fl2;

            // Byte-offset hash products for the lo corner (prime*4, wrap).
            const uint32_t q0 = ((uint32_t)(int32_t)fl0) << 2;   // prime 1
            const uint32_t q1 = ((uint32_t)(int32_t)fl1) * P1_4;
            const uint32_t q2 = ((uint32_t)(int32_t)fl2) * P2_4;
            // Masked XOR deltas per dim ((a^b)&M4).
            dd0[k] = (q0 ^ (q0 + 4u))   & M4;
            dd1[k] = (q1 ^ (q1 + P1_4)) & M4;
            dd2[k] = (q2 ^ (q2 + P2_4)) & M4;
            off[k] = (q0 ^ q1 ^ q2) & M4;            // corner 000 offset

            const _Float16 h0 = (_Float16)df0, h1 = (_Float16)df1,
                           hv2 = (_Float16)df2;
            tt0[k] = h2{h0, h0};
            tt1[k] = h2{h1, h1};
            tt2[k] = h2{hv2, hv2};
        }

        // ---- phase 2: 16 gathers in flight (gray-code XOR chains) ----
        h2 f[2][8];
#pragma unroll
        for (int k = 0; k < 2; ++k) {
            constexpr int gray[8] = {0, 1, 3, 2, 6, 7, 5, 4};
            uint32_t o = off[k];
#pragma unroll
            for (int j = 0; j < 8; ++j) {
                f[k][gray[j]] = *reinterpret_cast<const h2*>(tb + o);
                if (j < 7) {
                    const int tog = gray[j] ^ gray[j + 1];       // 4,2,1
                    o ^= (tog == 4) ? dd0[k] : (tog == 2) ? dd1[k] : dd2[k];
                }
            }
        }

        // ---- phase 3: two packed-fp16 lerp trees + direct stores ----
#pragma unroll
        for (int k = 0; k < 2; ++k) {
            h2 e0 = lerp2(f[k][0], f[k][1], tt2[k]);
            h2 e1 = lerp2(f[k][2], f[k][3], tt2[k]);
            h2 e2 = lerp2(f[k][4], f[k][5], tt2[k]);
            h2 e3 = lerp2(f[k][6], f[k][7], tt2[k]);
            h2 g0 = lerp2(e0, e1, tt1[k]);
            h2 g1 = lerp2(e2, e3, tt1[k]);
            h2 r  = lerp2(g0, g1, tt0[k]);
            out[(size_t)(n0 + pp + k) * L_LEVELS + l] =
                make_float2((float)r.x, (float)r.y);
        }
    }
}

extern "C" void kernel_launch(void* const* d_in, const int* in_sizes, int n_in,
                              void* d_out, int out_size, void* d_ws, size_t ws_size,
                              hipStream_t stream) {
    const float* x   = (const float*)d_in[0];
    const float* emb = (const float*)d_in[1];
    (void)d_ws; (void)ws_size;   // fill is unconditional; ws buys nothing.

    hash_encode_direct<<<1024, 512, 0, stream>>>(x, emb, (float2*)d_out);
}

// Round 7
// 87.294 us; speedup vs baseline: 1.0539x; 1.0539x over previous
//
#include <hip/hip_runtime.h>
#include <stdint.h>

constexpr int L_LEVELS = 16;
constexpr int T_SIZE   = 16384;
constexpr int N_PTS    = 262144;

typedef _Float16 h2 __attribute__((ext_vector_type(2)));
typedef _Float16 h4 __attribute__((ext_vector_type(4)));
typedef _Float16 h8 __attribute__((ext_vector_type(8)));

// Byte-offset-scaled hash constants: prime*4 mod 2^32, mask (T-1)*4.
constexpr uint32_t P1_4 = 2654435761u * 4u;
constexpr uint32_t P2_4 = 805459861u * 4u;
constexpr uint32_t M4   = (T_SIZE - 1) * 4u;   // 65532

__device__ __forceinline__ h2 lerp2(h2 a, h2 b, h2 t) {
    return a + t * (b - a);                     // v_pk_sub + v_pk_fma
}

// ---------------------------------------------------------------------------
// Session ledger:
//  * 256 MiB poison fill (~43-47 us) is UNCONDITIONAL -> fixed floor.
//  * Best measured pipeline: R0 = A(per-(level,chunk), in-block f32->fp16
//    staging, h2 (l,n) full-line ws stores) ~30 + B(transpose) ~9.
//  * R5: pre-converted fp16 tables = neutral (staging off critical path);
//    cvt prepass costs ~2.5 -> dropped.
//  * R6: direct (n,l) f32 scatter = REGRESSION (kernel ~49): partial-line
//    (8B @128B stride) stores amplify writes ~2x. Confirmed twice (R1).
//    -> results MUST leave A as 32B/thread contiguous h2; keep B.
//  * A is DS-LATENCY-bound (VALUBusy ~14%, DS-throughput floor ~10 us,
//    staging & occupancy levers both neutral). This round isolates ONE
//    lever: point-pair gather batching (16 outstanding ds_read_b32/wave).
// ---------------------------------------------------------------------------

// Kernel A: hash-encode, one (level, chunk-of-4096) per block, 512 thr x 8
// consecutive points, pair-batched gathers.
__global__ __launch_bounds__(512, 4) void hash_encode_lds(
    const float* __restrict__ x,
    const float* __restrict__ emb,    // (L, T, 2) f32
    h2*          __restrict__ res)    // (L, N) fp16 results (ws)
{
    __shared__ h2 tab[T_SIZE];        // 64 KB -> 2 blocks/CU, 16 waves/CU

    const int l     = blockIdx.x & (L_LEVELS - 1);
    const int chunk = blockIdx.x >> 4;             // 0..63
    const int t     = threadIdx.x;                 // 0..511
    const int n0    = chunk * 4096 + t * 8;        // 8 consecutive points

    // Stage table l: f32 -> fp16, 4096 h8 groups, 8 per thread (R0-proven).
    {
        const float4* __restrict__ src =
            reinterpret_cast<const float4*>(emb + (size_t)l * T_SIZE * 2);
        h8* __restrict__ d8 = reinterpret_cast<h8*>(tab);
#pragma unroll
        for (int it = 0; it < 8; ++it) {
            const int i = it * 512 + t;            // < 4096
            float4 a = src[2 * i];
            float4 b = src[2 * i + 1];
            h8 w = { (_Float16)a.x, (_Float16)a.y, (_Float16)a.z, (_Float16)a.w,
                     (_Float16)b.x, (_Float16)b.y, (_Float16)b.z, (_Float16)b.w };
            d8[i] = w;                             // ds_write_b128
        }
    }

    // This thread's 8 points: 96 B contiguous = 6 float4, kept in VGPRs.
    union { float4 q[6]; float f[24]; } xs;
    {
        const float4* __restrict__ xv =
            reinterpret_cast<const float4*>(x + (size_t)n0 * 3);
#pragma unroll
        for (int i = 0; i < 6; ++i) xs.q[i] = xv[i];
    }
    __syncthreads();

    // N_l = 16 * 2^(5l/16).
    const float Nl = 16.0f * exp2f((float)l * 0.3125f);
    const char* __restrict__ tb = reinterpret_cast<const char*>(tab);

    union { h2 r[8]; float4 q[2]; } out8;

#pragma unroll
    for (int pp = 0; pp < 8; pp += 2) {
        // ---- phase 1: both points' addresses + weights (pure VALU) ----
        uint32_t off[2], dd0[2], dd1[2], dd2[2];
        h2 tt0[2], tt1[2], tt2[2];
#pragma unroll
        for (int k = 0; k < 2; ++k) {
            const int p = pp + k;
            const float u0 = xs.f[3 * p + 0] * Nl;
            const float u1 = xs.f[3 * p + 1] * Nl;
            const float u2 = xs.f[3 * p + 2] * Nl;

            // u >= 0: df = u - floor(u); exact-integer case gives df=0
            // which zeroes the wrong-slot hi-corner lerp term -> correct.
            const float fl0 = floorf(u0), fl1 = floorf(u1), fl2 = floorf(u2);
            const float df0 = u0 - fl0, df1 = u1 - fl1, df2 = u2 - fl2;

            // Byte-offset hash products for the lo corner (prime*4, wrap).
            const uint32_t q0 = ((uint32_t)(int32_t)fl0) << 2;   // prime 1
            const uint32_t q1 = ((uint32_t)(int32_t)fl1) * P1_4;
            const uint32_t q2 = ((uint32_t)(int32_t)fl2) * P2_4;
            // Masked XOR deltas per dim ((a^b)&M4).
            dd0[k] = (q0 ^ (q0 + 4u))   & M4;
            dd1[k] = (q1 ^ (q1 + P1_4)) & M4;
            dd2[k] = (q2 ^ (q2 + P2_4)) & M4;
            off[k] = (q0 ^ q1 ^ q2) & M4;          // corner 000 offset

            const _Float16 h0 = (_Float16)df0, h1 = (_Float16)df1,
                           hv2 = (_Float16)df2;
            tt0[k] = h2{h0, h0};
            tt1[k] = h2{h1, h1};
            tt2[k] = h2{hv2, hv2};
        }

        // ---- phase 2: 16 gathers in flight (gray-code XOR chains) ----
        h2 f[2][8];
#pragma unroll
        for (int k = 0; k < 2; ++k) {
            constexpr int gray[8] = {0, 1, 3, 2, 6, 7, 5, 4};
            uint32_t o = off[k];
#pragma unroll
            for (int j = 0; j < 8; ++j) {
                f[k][gray[j]] = *reinterpret_cast<const h2*>(tb + o);
                if (j < 7) {
                    const int tog = gray[j] ^ gray[j + 1];       // 4,2,1
                    o ^= (tog == 4) ? dd0[k] : (tog == 2) ? dd1[k] : dd2[k];
                }
            }
        }

        // ---- phase 3: two packed-fp16 lerp trees ----
#pragma unroll
        for (int k = 0; k < 2; ++k) {
            h2 e0 = lerp2(f[k][0], f[k][1], tt2[k]);
            h2 e1 = lerp2(f[k][2], f[k][3], tt2[k]);
            h2 e2 = lerp2(f[k][4], f[k][5], tt2[k]);
            h2 e3 = lerp2(f[k][6], f[k][7], tt2[k]);
            h2 g0 = lerp2(e0, e1, tt1[k]);
            h2 g1 = lerp2(e2, e3, tt1[k]);
            out8.r[pp + k] = lerp2(g0, g1, tt0[k]);
        }
    }

    // Level results: 8 h2 = 32 B contiguous per thread -> full lines.
    {
        float4* __restrict__ o4 = reinterpret_cast<float4*>(
            res + (size_t)l * N_PTS + n0);
        o4[0] = out8.q[0];
        o4[1] = out8.q[1];
    }
}

// ---------------------------------------------------------------------------
// Kernel B: transpose+expand ws (L,N) fp16 -> out (N,L) f32 via LDS tile.
// 512 blocks x 256 thr, 512 points/block. h4 loads (8 B/lane), float4
// full-line stores (16 B/lane). Row pad +2 keeps h4 writes 8 B-aligned and
// read conflicts <= 2-way (free).
// ---------------------------------------------------------------------------
__global__ __launch_bounds__(256) void transpose_expand(
    const h2* __restrict__ res,
    float4*   __restrict__ out)
{
    __shared__ h2 tile[L_LEVELS][514];
    const int t    = threadIdx.x;
    const int base = blockIdx.x * 512;

#pragma unroll
    for (int l = 0; l < L_LEVELS; ++l) {
        h4 v = reinterpret_cast<const h4*>(res + (size_t)l * N_PTS + base)[t];
        *reinterpret_cast<h4*>(&tile[l][2 * t]) = v;     // 8 B-aligned
    }
    __syncthreads();

    float4* __restrict__ o = out + (size_t)base * 8;     // 512 pts x 8 f4
#pragma unroll
    for (int i = 0; i < L_LEVELS; ++i) {
        const int f    = i * 256 + t;                    // 0..4095
        const int p    = f >> 3;                         // point in tile
        const int part = f & 7;                          // f4 within row
        h2 a = tile[2 * part][p];
        h2 b = tile[2 * part + 1][p];
        o[f] = make_float4((float)a.x, (float)a.y,
                           (float)b.x, (float)b.y);      // 4 KB/instr
    }
}

// ---------------------------------------------------------------------------
// Fallback (ws too small): R3's workspace-free fused kernel (proven).
// ---------------------------------------------------------------------------
__global__ __launch_bounds__(1024, 4) void hash_encode_fused(
    const float* __restrict__ x,
    const float* __restrict__ emb,
    float4*      __restrict__ out)
{
    __shared__ union {
        h2 tab[2][T_SIZE];
        h2 tr[1024][20];
    } sm;

    const int t = threadIdx.x;
    const int n = blockIdx.x * 1024 + t;
    const int rot = (blockIdx.x << 4) & 4095;

    const float x0 = x[3 * n + 0];
    const float x1 = x[3 * n + 1];
    const float x2 = x[3 * n + 2];

    {
        const float4* __restrict__ s = reinterpret_cast<const float4*>(emb);
        h8* __restrict__ d = reinterpret_cast<h8*>(sm.tab[0]);
#pragma unroll
        for (int r = 0; r < 4; ++r) {
            const int j = (r * 1024 + t + rot) & 4095;
            float4 a = s[2 * j];
            float4 b = s[2 * j + 1];
            h8 w = { (_Float16)a.x, (_Float16)a.y, (_Float16)a.z, (_Float16)a.w,
                     (_Float16)b.x, (_Float16)b.y, (_Float16)b.z, (_Float16)b.w };
            d[j] = w;
        }
    }
    __syncthreads();

    union { h2 r[L_LEVELS]; h8 q[4]; } resu;

#pragma unroll
    for (int l = 0; l < L_LEVELS; ++l) {
        float4 sa0, sb0, sa1, sb1, sa2, sb2, sa3, sb3;
        int j0 = 0, j1 = 0, j2 = 0, j3 = 0;
        if (l < L_LEVELS - 1) {
            const float4* __restrict__ s = reinterpret_cast<const float4*>(
                emb + (size_t)(l + 1) * T_SIZE * 2);
            j0 = (0 * 1024 + t + rot) & 4095;
            j1 = (1 * 1024 + t + rot) & 4095;
            j2 = (2 * 1024 + t + rot) & 4095;
            j3 = (3 * 1024 + t + rot) & 4095;
            sa0 = s[2 * j0]; sb0 = s[2 * j0 + 1];
            sa1 = s[2 * j1]; sb1 = s[2 * j1 + 1];
            sa2 = s[2 * j2]; sb2 = s[2 * j2 + 1];
            sa3 = s[2 * j3]; sb3 = s[2 * j3 + 1];
        }

        const float Nl = 16.0f * exp2f((float)l * 0.3125f);
        const char* __restrict__ tb =
            reinterpret_cast<const char*>(sm.tab[l & 1]);

        const float u0 = x0 * Nl, u1 = x1 * Nl, u2 = x2 * Nl;
        const float fl0 = floorf(u0), fl1 = floorf(u1), fl2 = floorf(u2);
        const float df0 = u0 - fl0, df1 = u1 - fl1, df2 = u2 - fl2;

        const uint32_t q0 = ((uint32_t)(int32_t)fl0) << 2;
        const uint32_t q1 = ((uint32_t)(int32_t)fl1) * P1_4;
        const uint32_t q2 = ((uint32_t)(int32_t)fl2) * P2_4;
        const uint32_t d0 = (q0 ^ (q0 + 4u))   & M4;
        const uint32_t d1 = (q1 ^ (q1 + P1_4)) & M4;
        const uint32_t d2 = (q2 ^ (q2 + P2_4)) & M4;

        uint32_t off = (q0 ^ q1 ^ q2) & M4;

        constexpr int gray[8] = {0, 1, 3, 2, 6, 7, 5, 4};
        h2 f[8];
#pragma unroll
        for (int j = 0; j < 8; ++j) {
            f[gray[j]] = *reinterpret_cast<const h2*>(tb + off);
            if (j < 7) {
                const int tog = gray[j] ^ gray[j + 1];
                off ^= (tog == 4) ? d0 : (tog == 2) ? d1 : d2;
            }
        }

        const _Float16 h0 = (_Float16)df0, h1 = (_Float16)df1, hv2 = (_Float16)df2;
        const h2 t0 = {h0, h0}, t1 = {h1, h1}, t2 = {hv2, hv2};
        h2 e0 = lerp2(f[0], f[1], t2);
        h2 e1 = lerp2(f[2], f[3], t2);
        h2 e2 = lerp2(f[4], f[5], t2);
        h2 e3 = lerp2(f[6], f[7], t2);
        h2 g0 = lerp2(e0, e1, t1);
        h2 g1 = lerp2(e2, e3, t1);
        resu.r[l] = lerp2(g0, g1, t0);

        if (l < L_LEVELS - 1) {
            h8* __restrict__ d = reinterpret_cast<h8*>(sm.tab[(l + 1) & 1]);
            h8 w0 = { (_Float16)sa0.x, (_Float16)sa0.y, (_Float16)sa0.z, (_Float16)sa0.w,
                      (_Float16)sb0.x, (_Float16)sb0.y, (_Float16)sb0.z, (_Float16)sb0.w };
            h8 w1 = { (_Float16)sa1.x, (_Float16)sa1.y, (_Float16)sa1.z, (_Float16)sa1.w,
                      (_Float16)sb1.x, (_Float16)sb1.y, (_Float16)sb1.z, (_Float16)sb1.w };
            h8 w2 = { (_Float16)sa2.x, (_Float16)sa2.y, (_Float16)sa2.z, (_Float16)sa2.w,
                      (_Float16)sb2.x, (_Float16)sb2.y, (_Float16)sb2.z, (_Float16)sb2.w };
            h8 w3 = { (_Float16)sa3.x, (_Float16)sa3.y, (_Float16)sa3.z, (_Float16)sa3.w,
                      (_Float16)sb3.x, (_Float16)sb3.y, (_Float16)sb3.z, (_Float16)sb3.w };
            d[j0] = w0;
            d[j1] = w1;
            d[j2] = w2;
            d[j3] = w3;
            __syncthreads();
        }
    }

    __syncthreads();
#pragma unroll
    for (int g = 0; g < 4; ++g)
        *reinterpret_cast<h8*>(&sm.tr[t][4 * g]) = resu.q[g];
    __syncthreads();

    float4* __restrict__ o = out + (size_t)blockIdx.x * 8192;
#pragma unroll
    for (int i = 0; i < 8; ++i) {
        const int p  = i * 128 + (t >> 3);
        const int l0 = 2 * (t & 7);
        h4 v = *reinterpret_cast<const h4*>(&sm.tr[p][l0]);
        o[i * 1024 + t] = make_float4((float)v.x, (float)v.y,
                                      (float)v.z, (float)v.w);
    }
}

extern "C" void kernel_launch(void* const* d_in, const int* in_sizes, int n_in,
                              void* d_out, int out_size, void* d_ws, size_t ws_size,
                              hipStream_t stream) {
    const float* x   = (const float*)d_in[0];
    const float* emb = (const float*)d_in[1];

    const size_t need = (size_t)L_LEVELS * N_PTS * sizeof(h2);  // 16 MiB

    if (ws_size >= need) {
        h2* res = (h2*)d_ws;
        hash_encode_lds<<<1024, 512, 0, stream>>>(x, emb, res);
        transpose_expand<<<512, 256, 0, stream>>>(res, (float4*)d_out);
    } else {
        hash_encode_fused<<<256, 1024, 0, stream>>>(x, emb, (float4*)d_out);
    }
}